// Round 3
// baseline (503.295 us; speedup 1.0000x reference)
//
#include <hip/hip_runtime.h>

#define NUM_CLASSES 601
#define OUT_DIM 27
#define P_ELEMS (NUM_CLASSES * OUT_DIM)   // 16227 floats = 64908 B LDS (< 64 KiB static limit)

// Vanilla config: block=512 (8 waves), no waves-per-EU contract, plain float4 stores.
// LDS 64908 B -> 2 blocks/CU -> 16 waves/CU; enough TLP for a store-streaming kernel.
__global__ __launch_bounds__(512)
void trigram_probs_kernel(const int* __restrict__ idx,
                          const float* __restrict__ W,
                          float4* __restrict__ out4,
                          unsigned n4) {
    __shared__ float P[P_ELEMS];
    const unsigned t = threadIdx.x;

    // ---- Preamble: softmax(W) -> LDS. 512 threads cover 601 rows in 2 strides.
    // Two-pass per row (re-compute exp) keeps VGPR pressure low.
    for (unsigned row = t; row < NUM_CLASSES; row += 512u) {
        const float* w = W + row * OUT_DIM;
        float s = 0.f;
        #pragma unroll
        for (int j = 0; j < OUT_DIM; ++j) s += __expf(w[j]);
        const float inv = 1.0f / s;
        #pragma unroll
        for (int j = 0; j < OUT_DIM; ++j) P[row * OUT_DIM + j] = __expf(w[j]) * inv;
    }
    __syncthreads();

    // ---- Main loop: flat float4 gather-store. Element e -> row e/27, col e%27.
    // One float4 spans at most 2 rows: fetch both row indices unconditionally
    // (r1 = (e+3)/27 <= B-1 always since e+3 <= total-1) and select per lane-element.
    unsigned i = blockIdx.x * blockDim.x + t;
    const unsigned stride = gridDim.x * blockDim.x;
    for (; i < n4; i += stride) {
        const unsigned e  = i * 4u;
        const unsigned r0 = e / 27u;              // magic-multiply
        const unsigned c0 = e - r0 * 27u;
        const unsigned r1 = (e + 3u) / 27u;
        const int base0 = idx[r0] * OUT_DIM;
        const int base1 = idx[r1] * OUT_DIM;
        float v[4];
        #pragma unroll
        for (int k = 0; k < 4; ++k) {
            const unsigned c = c0 + (unsigned)k;
            const int a = (c < 27u) ? (base0 + (int)c) : (base1 + (int)(c - 27u));
            v[k] = P[a];
        }
        out4[i] = make_float4(v[0], v[1], v[2], v[3]);
    }
}

extern "C" void kernel_launch(void* const* d_in, const int* in_sizes, int n_in,
                              void* d_out, int out_size, void* d_ws, size_t ws_size,
                              hipStream_t stream) {
    const int*   idx = (const int*)d_in[0];   // bigram_idx [4194304] int32
    const float* W   = (const float*)d_in[1]; // W [601,27] float32
    float4*      out = (float4*)d_out;        // probs [4194304,27] float32

    const unsigned n4 = (unsigned)(out_size / 4);  // 113246208/4 = 28311552, exact
    trigram_probs_kernel<<<dim3(512), dim3(512), 0, stream>>>(idx, W, out, n4);
}